// Round 12
// baseline (57.372 us; speedup 1.0000x reference)
//
#include <hip/hip_runtime.h>
#include <math.h>

constexpr int H_ = 180, W_ = 320, RF_ = 16, K_ = 20, T_ = 400;
constexpr int HW_ = H_ * W_;
constexpr int NWIN = T_ - K_ + 1;   // 381
constexpr int PW   = W_ + 2 * RF_;  // 352
constexpr float ALPHA = 50.0f, BETA = 1.0f, GAMMA = 0.0f;

constexpr int BSTEP  = 28;                    // rows owned per band
constexpr int NBANDS = 6;                     // r0c in [0,164] -> bands 0..5
constexpr int BROWS  = 43;                    // staged rows = BSTEP + 15
constexpr int RP     = 328;                   // LDS row stride (words)
constexpr int CHUNKS = (BROWS * RP + 255) / 256;  // 56 x 1KB DMA chunks
constexpr int BUFW   = CHUNKS * 256;          // 14336 words per buffer
constexpr int WPR = 36, WROWS = 32;           // padded weight table
constexpr int LDSW_W = WROWS * WPR;           // 1152 words
constexpr int CF = 10;                        // frames per block
constexpr int NCHUNKS_T = T_ / CF;            // 40

// ---------------------------------------------------------------------------
// VALU-pipe cross-lane primitives (proven R10)
// ---------------------------------------------------------------------------
template <int CTRL>
__device__ inline float dpp_add(float v) {
    int s = __builtin_amdgcn_update_dpp(0, __float_as_int(v), CTRL, 0xF, 0xF, true);
    return v + __int_as_float(s);
}
__device__ inline float swz_xor4_add(float v) {
    return v + __int_as_float(
        __builtin_amdgcn_ds_swizzle(__float_as_int(v), 0x101F));  // lane^4
}
#if __has_builtin(__builtin_amdgcn_permlane32_swap)
__device__ inline float pl32_merge(float a, float b) {
    auto r = __builtin_amdgcn_permlane32_swap(
        __float_as_uint(a), __float_as_uint(b), false, false);
    return __uint_as_float(r[0]) + __uint_as_float(r[1]);
}
#else
__device__ inline float pl32_merge(float a, float b) {
    bool hi = (threadIdx.x & 32) != 0;
    float keep = hi ? b : a, send = hi ? a : b;
    return keep + __shfl_xor(send, 32, 64);
}
#endif
#if __has_builtin(__builtin_amdgcn_permlane16_swap)
__device__ inline float pl16_merge(float a, float b) {
    auto r = __builtin_amdgcn_permlane16_swap(
        __float_as_uint(a), __float_as_uint(b), false, false);
    return __uint_as_float(r[0]) + __uint_as_float(r[1]);
}
#else
__device__ inline float pl16_merge(float a, float b) {
    bool hi = (threadIdx.x & 16) != 0;
    float keep = hi ? b : a, send = hi ? a : b;
    return keep + __shfl_xor(send, 16, 64);
}
#endif
__device__ inline float allred64(float v) {
    v = dpp_add<0xB1>(v);    // xor 1
    v = dpp_add<0x4E>(v);    // xor 2
    v = swz_xor4_add(v);     // xor 4
    v = dpp_add<0x128>(v);   // xor 8 (row_ror:8)
    v = pl16_merge(v, v);    // xor 16
    v = pl32_merge(v, v);    // xor 32
    return v;
}
// reduce within each 16-lane group (all lanes of group end with the sum)
__device__ inline float red16(float v) {
    v = dpp_add<0xB1>(v);
    v = dpp_add<0x4E>(v);
    v = swz_xor4_add(v);
    v = dpp_add<0x128>(v);
    return v;
}

// ---------------------------------------------------------------------------
// prep: waves 0..7 factorize w (exact rank-1) -> temporal[K] + pivot row;
// waves 8..15 bucket neurons into 6 row-bands with LDS descriptors
// {n, window word base, padded-weight word base}; then build the zero-padded
// weight table spat_pad[32][36]. Single block; deterministic output.
// ---------------------------------------------------------------------------
__global__ __launch_bounds__(1024) void prep_kernel(
    const float* __restrict__ w, const int* __restrict__ rf,
    float* __restrict__ temporal, float* __restrict__ spat_pad,
    int* __restrict__ cnt, int4* __restrict__ lists, int N)
{
    __shared__ float ss[32];
    int tid = threadIdx.x, wv = tid >> 6, l = tid & 63;
    if (tid < NBANDS) cnt[tid] = 0;
    __syncthreads();

    if (wv < 8) {
        for (int k = wv; k < K_; k += 8) {
            float s = 0.0f;
#pragma unroll
            for (int j = 0; j < 4; ++j) {
                float v = w[k * 256 + l + j * 64];
                s = fmaf(v, v, s);
            }
            s = allred64(s);
            if (l == 0) ss[k] = s;
        }
    } else {
        for (int n = tid - 512; n < N; n += 512) {
            int base = rf[n * 256];
            int v0 = base / PW;
            int r0 = v0 - RF_;
            int c0 = (base - v0 * PW) - RF_;
            int r0c = min(max(r0, 0), H_ - RF_);
            int c0c = min(max(c0, 0), W_ - RF_);
            int b = r0c / BSTEP;
            int slot = atomicAdd(&cnt[b], 1);
            int4 d;
            d.x = n;
            d.y = (r0c - b * BSTEP) * RP + c0c;           // window base (words)
            d.z = (r0c - r0 + 8) * WPR + (c0c - c0 + 8);  // padded-w base
            d.w = 0;
            lists[b * N + slot] = d;
        }
    }
    __syncthreads();

    float best = -1.0f;
    int k0 = 0;
    for (int k = 0; k < K_; ++k) {
        float v = ss[k];
        if (v > best) { best = v; k0 = k; }
    }

    if (wv < 8) {
        for (int k = wv; k < K_; k += 8) {
            float d = 0.0f;
#pragma unroll
            for (int j = 0; j < 4; ++j)
                d = fmaf(w[k * 256 + l + j * 64], w[k0 * 256 + l + j * 64], d);
            d = allred64(d);
            if (l == 0) temporal[k] = d / best;
        }
    }
    for (int i = tid; i < LDSW_W; i += 1024) {
        int rr = i / WPR - 8;
        int cc = i % WPR - 8;
        bool ok = (rr >= 0) & (rr < RF_) & (cc >= 0) & (cc < RF_);
        spat_pad[i] = ok ? w[k0 * 256 + rr * RF_ + cc] : 0.0f;
    }
}

// ---------------------------------------------------------------------------
// Stage 1: y[n, t] = sum_p x_patch[t, n, p] * spatial[p]
//
// Block = (band b, 10-frame range). Double-buffered LDS frame-bands staged
// via global_load_lds width-16 (per-lane global source supplies the row
// padding; linear LDS dest). Per frame: every band-neuron computed from LDS
// by a 16-lane row group: 4 ds_read_b128 window + 4 ds_read_b128 shifted
// zero-padded weights (both 16B-aligned for any neuron), 16 FMA, DPP reduce.
// Each global line is fetched exactly once per block (streamed, not
// gathered) -> ~138 MB of line fills vs ~630 MB for the gather kernels.
// ---------------------------------------------------------------------------
__global__ __launch_bounds__(1024) void stage1_kernel(
    const float* __restrict__ x, const float* __restrict__ spat_pad,
    const int* __restrict__ cnt, const int4* __restrict__ lists,
    float* __restrict__ y, int N)
{
    __shared__ float lds[2 * BUFW + LDSW_W];   // 116.5 KB
    float* ldsw = lds + 2 * BUFW;

    int tid  = threadIdx.x;
    int wv   = tid >> 6;
    int lane = tid & 63;

    int b       = blockIdx.x % NBANDS;
    int chunkid = blockIdx.x / NBANDS;
    int f0      = chunkid * CF;
    int band0   = b * BSTEP;

    // weight table -> LDS
    for (int i = tid; i < LDSW_W; i += 1024) ldsw[i] = spat_pad[i];

    int count = cnt[b];
    const int4* list = lists + (size_t)b * N;
    int g = lane >> 4;   // neuron sub-group 0..3
    int r = lane & 15;   // window row

    // ---- staging: frame f -> buffer sel (issue only; no wait) ----
    auto stage = [&](int sel, int f) {
        const float* xf = x + (size_t)f * HW_;
        for (int ck = wv; ck < CHUNKS; ck += 16) {
            int w0  = ck * 256 + lane * 4;
            int row = w0 / RP;
            int col = w0 - row * RP;
            int srow = min(band0 + row, H_ - 1);
            int scol = min(col, W_ - 4);
            const float* gp = xf + srow * W_ + scol;
            __builtin_amdgcn_global_load_lds(
                (const __attribute__((address_space(1))) void*)gp,
                (__attribute__((address_space(3))) void*)(lds + sel * BUFW + ck * 256),
                16, 0, 0);
        }
    };

    // ---- compute: all band neurons for frame t from buffer sel ----
    auto compute = [&](int sel, int t) {
        const float* buf = lds + sel * BUFW;
        for (int i = wv * 4 + g; i < count; i += 64) {
            int4 d = list[i];
            int ax = d.y + r * RP;
            int aw = d.z + r * WPR;
            float a = 0.0f;
#pragma unroll
            for (int q = 0; q < 4; ++q) {
                float4 pv = *reinterpret_cast<const float4*>(buf + ax + q * 4);
                float4 wq = *reinterpret_cast<const float4*>(ldsw + aw + q * 4);
                a = fmaf(pv.x, wq.x, a);
                a = fmaf(pv.y, wq.y, a);
                a = fmaf(pv.z, wq.z, a);
                a = fmaf(pv.w, wq.w, a);
            }
            a = red16(a);
            if (r == 0) y[(size_t)d.x * T_ + t] = a;
        }
    };

    stage(0, f0);
    __syncthreads();             // drains DMA (compiler emits vmcnt(0) here)
    for (int j = 0; j < CF; ++j) {
        if (j + 1 < CF) stage((j + 1) & 1, f0 + j + 1);
        compute(j & 1, f0 + j);
        __syncthreads();         // joins waves + drains next frame's DMA
    }
}

// ---------------------------------------------------------------------------
// Stage 2: out[n, t0] = ALPHA * softplus(BETA * (sum_k y[n,t0+k]*temporal[k]
//                                                 - GAMMA))
// ---------------------------------------------------------------------------
__global__ void stage2_kernel(const float* __restrict__ y,
                              const float* __restrict__ temporal,
                              float* __restrict__ out, int N)
{
    __shared__ float tw[K_];
    if (threadIdx.x < K_) tw[threadIdx.x] = temporal[threadIdx.x];
    __syncthreads();

    int n  = blockIdx.x;
    int t0 = threadIdx.x;
    if (n >= N || t0 >= NWIN) return;

    const float* yn = y + (size_t)n * T_;
    float g = 0.0f;
#pragma unroll
    for (int k = 0; k < K_; ++k)
        g = fmaf(yn[t0 + k], tw[k], g);

    float z = BETA * (g - GAMMA);
    float sp = fmaxf(z, 0.0f) + log1pf(expf(-fabsf(z)));
    out[n * NWIN + t0] = ALPHA * sp;
}

// ---------------------------------------------------------------------------
extern "C" void kernel_launch(void* const* d_in, const int* in_sizes, int n_in,
                              void* d_out, int out_size, void* d_ws, size_t ws_size,
                              hipStream_t stream)
{
    const float* x  = (const float*)d_in[0];  // (T, H, W) f32
    const float* w  = (const float*)d_in[1];  // (K*RF*RF,) f32
    const int*   rf = (const int*)d_in[2];    // (N, 256) i32

    int N = in_sizes[2] / (RF_ * RF_);

    // ws layout (4B words):
    // [0,64)   temporal | [64,128) cnt | [128,1280) spat_pad |
    // [1280, 1280+4*NBANDS*N) lists (int4) | y : N*T
    float* temporal = (float*)d_ws;
    int*   cnt      = (int*)d_ws + 64;
    float* spat_pad = (float*)d_ws + 128;
    int4*  lists    = (int4*)((int*)d_ws + 1280);
    float* y        = (float*)d_ws + 1280 + 4 * NBANDS * N;

    prep_kernel<<<1, 1024, 0, stream>>>(w, rf, temporal, spat_pad, cnt, lists, N);
    stage1_kernel<<<NCHUNKS_T * NBANDS, 1024, 0, stream>>>(x, spat_pad, cnt, lists, y, N);
    stage2_kernel<<<N, 384, 0, stream>>>(y, temporal, (float*)d_out, N);
}

// Round 13
// 40.830 us; speedup vs baseline: 1.4051x; 1.4051x over previous
//
#include <hip/hip_runtime.h>
#include <math.h>

constexpr int H_ = 180, W_ = 320, RF_ = 16, K_ = 20, T_ = 400;
constexpr int HW_ = H_ * W_;
constexpr int NWIN = T_ - K_ + 1;   // 381
constexpr int PW   = W_ + 2 * RF_;  // 352 (padded width used by rf_indices)
constexpr float ALPHA = 50.0f, BETA = 1.0f, GAMMA = 0.0f;
constexpr int NXCD = 8;
constexpr int T_PER_XCD = T_ / NXCD;     // 50 frames per XCD
constexpr int T_HALF = T_PER_XCD / 2;    // 25 frames per wave
constexpr int CH = 8;                    // frames per reduction chunk

// ---------------------------------------------------------------------------
// VALU-pipe cross-lane primitives (proven R10/R11)
// ---------------------------------------------------------------------------
template <int CTRL>
__device__ inline float dpp_add(float v) {
    int s = __builtin_amdgcn_update_dpp(0, __float_as_int(v), CTRL, 0xF, 0xF, true);
    return v + __int_as_float(s);
}
__device__ inline float swz_xor4_add(float v) {
    return v + __int_as_float(
        __builtin_amdgcn_ds_swizzle(__float_as_int(v), 0x101F));  // lane^4
}
#if __has_builtin(__builtin_amdgcn_permlane32_swap)
__device__ inline float pl32_merge(float a, float b) {
    auto r = __builtin_amdgcn_permlane32_swap(
        __float_as_uint(a), __float_as_uint(b), false, false);
    return __uint_as_float(r[0]) + __uint_as_float(r[1]);
}
#else
__device__ inline float pl32_merge(float a, float b) {
    bool hi = (threadIdx.x & 32) != 0;
    float keep = hi ? b : a, send = hi ? a : b;
    return keep + __shfl_xor(send, 32, 64);
}
#endif
#if __has_builtin(__builtin_amdgcn_permlane16_swap)
__device__ inline float pl16_merge(float a, float b) {
    auto r = __builtin_amdgcn_permlane16_swap(
        __float_as_uint(a), __float_as_uint(b), false, false);
    return __uint_as_float(r[0]) + __uint_as_float(r[1]);
}
#else
__device__ inline float pl16_merge(float a, float b) {
    bool hi = (threadIdx.x & 16) != 0;
    float keep = hi ? b : a, send = hi ? a : b;
    return keep + __shfl_xor(send, 16, 64);
}
#endif
__device__ inline float allred64(float v) {
    v = dpp_add<0xB1>(v);    // xor 1
    v = dpp_add<0x4E>(v);    // xor 2
    v = swz_xor4_add(v);     // xor 4
    v = dpp_add<0x128>(v);   // xor 8 (row_ror:8)
    v = pl16_merge(v, v);    // xor 16
    v = pl32_merge(v, v);    // xor 32
    return v;
}

// 8-value multi-reduce over the wave (proven R10): input acc[0..7] per lane,
// output: lane 8j holds the full wave-sum of logical acc[j].
__device__ inline float multired8(const float* acc, bool b8) {
    float m0 = pl32_merge(acc[0], acc[4]);
    float m1 = pl32_merge(acc[1], acc[5]);
    float m2 = pl32_merge(acc[2], acc[6]);
    float m3 = pl32_merge(acc[3], acc[7]);
    float n0 = pl16_merge(m0, m2);
    float n1 = pl16_merge(m1, m3);
    float c0v = dpp_add<0x128>(n0);
    float c1v = dpp_add<0x128>(n1);
    float C = b8 ? c1v : c0v;
    C = dpp_add<0xB1>(C);
    C = dpp_add<0x4E>(C);
    C = swz_xor4_add(C);
    return C;
}

// ---------------------------------------------------------------------------
// prep: (a) factorize w (exact rank-1) -> spatial[256] + temporal[K] (waves
// 0-7); (b) build PAIR TASKS (waves 8-15): neurons (2i, 2i+1) sharing the
// same padded row (=> same y, same row clamp) become one task; otherwise
// degenerate single tasks (n,n). Descriptor: {n1|n2<<16, A word base,
// delta words, packed (dr, dc1, dc2) weight shifts}.
// ---------------------------------------------------------------------------
__global__ __launch_bounds__(1024) void prep_kernel(
    const float* __restrict__ w, const int* __restrict__ rf,
    float* __restrict__ spatial, float* __restrict__ temporal,
    int* __restrict__ cnt, int4* __restrict__ tasks, int N)
{
    __shared__ float ss[32];
    int tid = threadIdx.x, wv = tid >> 6, l = tid & 63;
    if (tid == 0) *cnt = 0;
    __syncthreads();

    if (wv < 8) {
        for (int k = wv; k < K_; k += 8) {
            float s = 0.0f;
#pragma unroll
            for (int j = 0; j < 4; ++j) {
                float v = w[k * 256 + l + j * 64];
                s = fmaf(v, v, s);
            }
            s = allred64(s);
            if (l == 0) ss[k] = s;
        }
    } else {
        for (int i = tid - 512; 2 * i < N; i += 512) {
            int n1 = 2 * i, n2 = 2 * i + 1;
            int b1 = rf[n1 * 256];
            int v1 = b1 / PW;
            int pn2 = n1, b2 = b1, v2 = v1;
            bool paired = false;
            if (n2 < N) {
                b2 = rf[n2 * 256];
                v2 = b2 / PW;
                paired = (v2 == v1);
            }
            // emit task for (n1, paired ? n2 : n1)
            {
                int r0  = v1 - RF_;
                int c01 = (b1 - v1 * PW) - RF_;
                int r0c = min(max(r0, 0), H_ - RF_);
                int c0c1 = min(max(c01, 0), W_ - RF_);
                int c02  = paired ? ((b2 - v2 * PW) - RF_) : c01;
                int c0c2 = min(max(c02, 0), W_ - RF_);
                pn2 = paired ? n2 : n1;
                int4 d;
                d.x = n1 | (pn2 << 16);
                d.y = r0c * W_ + c0c1;
                d.z = c0c2 - c0c1;
                d.w = (r0c - r0 + 8) | ((c0c1 - c01 + 8) << 8)
                                     | ((c0c2 - c02 + 8) << 16);
                tasks[atomicAdd(cnt, 1)] = d;
            }
            if (!paired && n2 < N) {   // n2 as its own single task
                int r0  = v2 - RF_;
                int c02 = (b2 - v2 * PW) - RF_;
                int r0c = min(max(r0, 0), H_ - RF_);
                int c0c2 = min(max(c02, 0), W_ - RF_);
                int4 d;
                d.x = n2 | (n2 << 16);
                d.y = r0c * W_ + c0c2;
                d.z = 0;
                d.w = (r0c - r0 + 8) | ((c0c2 - c02 + 8) << 8)
                                     | ((c0c2 - c02 + 8) << 16);
                tasks[atomicAdd(cnt, 1)] = d;
            }
        }
    }
    __syncthreads();

    float best = -1.0f;
    int k0 = 0;
    for (int k = 0; k < K_; ++k) {
        float v = ss[k];
        if (v > best) { best = v; k0 = k; }
    }
    if (wv < 8) {
        for (int k = wv; k < K_; k += 8) {
            float d = 0.0f;
#pragma unroll
            for (int j = 0; j < 4; ++j)
                d = fmaf(w[k * 256 + l + j * 64], w[k0 * 256 + l + j * 64], d);
            d = allred64(d);
            if (l == 0) temporal[k] = d / best;
        }
    }
    if (tid < 256) spatial[tid] = w[k0 * 256 + tid];
}

// ---------------------------------------------------------------------------
// Stage 1 (pair-gather): one wave = one neuron PAIR x 25 frames.
// Lane (r = lane>>2, s = lane&3) loads chunk s of window1 (A) and chunk s of
// window2 (B = A + delta*4B, delta <= 8 px) -> the pair's union rows touch
// ~2.25 lines instead of 3.5 (1.53x fewer L1 line-fills); request count per
// neuron unchanged. Same weight float4 feeds both accumulators (shifted-
// weight trick handles clamped borders; dc is always a multiple of 4 on the
// mosaic lattice). 8-frame chunks; two multired8 per chunk; lane 8j stores
// frame j. Degenerate tasks (n,n) reuse the identical path.
// ---------------------------------------------------------------------------
__global__ __launch_bounds__(256) void stage1_kernel(
    const float* __restrict__ x, const int4* __restrict__ tasks,
    const int* __restrict__ cnt, const float* __restrict__ spatial,
    float* __restrict__ y)
{
    int lane = threadIdx.x & 63;
    int wid  = threadIdx.x >> 6;

    int b    = blockIdx.x;
    int xcd  = b & (NXCD - 1);
    int rest = b >> 3;
    int half = rest & 1;
    int tg   = rest >> 1;

    int taskid = tg * 4 + wid;
    if (taskid >= *cnt) return;

    int4 d = tasks[taskid];
    int n1 = d.x & 0xFFFF;
    int n2 = d.x >> 16;
    int delta = d.z;
    int dr  = (d.w & 0xFF) - 8;
    int dc1 = ((d.w >> 8) & 0xFF) - 8;
    int dc2 = ((d.w >> 16) & 0xFF) - 8;

    int t0 = xcd * T_PER_XCD + half * T_HALF;

    int r = lane >> 2;
    int s = lane & 3;

    // weights (float4 from spatial or zero; dc multiple of 4)
    int rr = r + dr;
    bool rok = (rr >= 0) & (rr < RF_);
    int cc1 = 4 * s + dc1;
    int cc2 = 4 * s + dc2;
    float4 w1 = make_float4(0.f, 0.f, 0.f, 0.f), w2 = w1;
    if (rok & (cc1 >= 0) & (cc1 < RF_))
        w1 = *reinterpret_cast<const float4*>(spatial + rr * RF_ + cc1);
    if (rok & (cc2 >= 0) & (cc2 < RF_))
        w2 = *reinterpret_cast<const float4*>(spatial + rr * RF_ + cc2);

    int offA = d.y + r * W_ + 4 * s;
    const float* xp = x + (size_t)t0 * HW_;
    float* yp1 = y + (size_t)n1 * T_ + t0;
    float* yp2 = y + (size_t)n2 * T_ + t0;

    bool b8 = (lane & 8) != 0;

    // 3 full chunks of 8 frames (local 0..23)
    for (int tt = 0; tt < 24; tt += CH) {
        float4 A[CH], B[CH];
#pragma unroll
        for (int j = 0; j < CH; ++j) {
            const float* fp = xp + (size_t)(tt + j) * HW_ + offA;
            A[j] = *reinterpret_cast<const float4*>(fp);
            B[j] = *reinterpret_cast<const float4*>(fp + delta);
        }
        float a1[CH], a2[CH];
#pragma unroll
        for (int j = 0; j < CH; ++j) {
            float u = A[j].x * w1.x;
            u = fmaf(A[j].y, w1.y, u);
            u = fmaf(A[j].z, w1.z, u);
            a1[j] = fmaf(A[j].w, w1.w, u);
            float v = B[j].x * w2.x;
            v = fmaf(B[j].y, w2.y, v);
            v = fmaf(B[j].z, w2.z, v);
            a2[j] = fmaf(B[j].w, w2.w, v);
        }
        float C1 = multired8(a1, b8);
        float C2 = multired8(a2, b8);
        if ((lane & 7) == 0) {
            yp1[tt + (lane >> 3)] = C1;
            yp2[tt + (lane >> 3)] = C2;
        }
    }

    // tail frame (local 24)
    {
        const float* fp = xp + (size_t)24 * HW_ + offA;
        float4 A = *reinterpret_cast<const float4*>(fp);
        float4 B = *reinterpret_cast<const float4*>(fp + delta);
        float u = A.x * w1.x;
        u = fmaf(A.y, w1.y, u);
        u = fmaf(A.z, w1.z, u);
        u = fmaf(A.w, w1.w, u);
        float v = B.x * w2.x;
        v = fmaf(B.y, w2.y, v);
        v = fmaf(B.z, w2.z, v);
        v = fmaf(B.w, w2.w, v);
        u = allred64(u);
        v = allred64(v);
        if (lane == 0) {
            yp1[24] = u;
            yp2[24] = v;
        }
    }
}

// ---------------------------------------------------------------------------
// Stage 2: out[n, t0] = ALPHA * softplus(BETA * (sum_k y[n,t0+k]*temporal[k]
//                                                 - GAMMA))
// ---------------------------------------------------------------------------
__global__ void stage2_kernel(const float* __restrict__ y,
                              const float* __restrict__ temporal,
                              float* __restrict__ out, int N)
{
    __shared__ float tw[K_];
    if (threadIdx.x < K_) tw[threadIdx.x] = temporal[threadIdx.x];
    __syncthreads();

    int n  = blockIdx.x;
    int t0 = threadIdx.x;
    if (n >= N || t0 >= NWIN) return;

    const float* yn = y + (size_t)n * T_;
    float g = 0.0f;
#pragma unroll
    for (int k = 0; k < K_; ++k)
        g = fmaf(yn[t0 + k], tw[k], g);

    float z = BETA * (g - GAMMA);
    float sp = fmaxf(z, 0.0f) + log1pf(expf(-fabsf(z)));
    out[n * NWIN + t0] = ALPHA * sp;
}

// ---------------------------------------------------------------------------
extern "C" void kernel_launch(void* const* d_in, const int* in_sizes, int n_in,
                              void* d_out, int out_size, void* d_ws, size_t ws_size,
                              hipStream_t stream)
{
    const float* x  = (const float*)d_in[0];  // (T, H, W) f32
    const float* w  = (const float*)d_in[1];  // (K*RF*RF,) f32
    const int*   rf = (const int*)d_in[2];    // (N, 256) i32

    int N = in_sizes[2] / (RF_ * RF_);

    // ws layout (4B words): [0,256) spatial | [256,320) temporal |
    // [320,384) cnt | [384, 384+4N) tasks (int4) | y : N*T
    float* spatial  = (float*)d_ws;
    float* temporal = spatial + 256;
    int*   cnt      = (int*)d_ws + 320;
    int4*  tasks    = (int4*)((int*)d_ws + 384);
    float* y        = (float*)d_ws + 384 + 4 * N;

    // grid sized for worst case (all singles = N tasks); excess waves exit.
    int NTG = (N + 3) / 4;
    prep_kernel<<<1, 1024, 0, stream>>>(w, rf, spatial, temporal, cnt, tasks, N);
    stage1_kernel<<<NXCD * NTG * 2, 256, 0, stream>>>(x, tasks, cnt, spatial, y);
    stage2_kernel<<<N, 384, 0, stream>>>(y, temporal, (float*)d_out, N);
}